// Round 7
// baseline (954.150 us; speedup 1.0000x reference)
//
#include <hip/hip_runtime.h>
#include <hip/hip_bf16.h>

#define BN 2
#define C0 64
#define HH 160
#define WW 160
#define HWn (HH*WW)          // 25600
#define PN (BN*HWn)          // 51200
#define DWCH 128
#define OMC 108

#define S128 ((long)PN*128)
#define S108 ((long)PN*108)
#define S64v ((long)PN*64)

// ---- phase-1 weight pack (lives in fR region; fR written only by side-1 k_outp)
#define W1_PW1T   0        // [64c][128o] pw1_w * ln1_g[c], transposed
#define W1_RS1    8192     // [128] rowsum of pw1T over c
#define W1_PB1    8320     // [128]
#define W1_VALT   8448     // [128c][128o]
#define W1_VB     24832    // [128]
#define W1_DWC    24960    // [1152]
#define W1_DWB    26112    // [128]
#define W1_OMT    26240    // [128c][108o]
#define W1_OMB    40064    // [108]
#define W1_OUTT   40172    // [128c][128o]
#define W1_OUTB   56556    // [128]
// ---- phase-2 weight pack (Bv+26000; v dead after side-1 k_samp)
#define WB_OUTT   0        // [128c][128o]
#define WB_OUTB   16384
#define WB_C3T    16512    // [128c][64o]
#define WB_C3B    24704
#define WB_BETA   24768
#define WB_W4T    24832    // [128c][128o] conv4_w * norm2_g[c], transposed
#define WB_RS4    41216
#define WB_B4     41344
#define WB_W5T    41472    // [64c][64o] conv5_w * gamma[o], transposed
#define WB_B5G    45568    // [64] conv5_b * gamma

__device__ __forceinline__ float ldin(const void* p, long i, int bf) {
  return bf ? __bfloat162float(((const __hip_bfloat16*)p)[i])
            : ((const float*)p)[i];
}
__device__ __forceinline__ void stout(void* p, long i, float v, int bf) {
  if (bf) ((__hip_bfloat16*)p)[i] = __float2bfloat16(v);
  else    ((float*)p)[i] = v;
}

// ---- dtype probe
__global__ void k_flag(const void* g1, int* flag) {
  unsigned w = *(const unsigned*)g1;
  *flag = (w == 0x3F800000u) ? 0 : 1;
}

// ---- weight conversion, phase 1 (into fR region)
__global__ void k_conv1(const void* pw1_w, const void* ln1_g, const void* pw1_b,
                        const void* val_w, const void* val_b,
                        const void* dwc_w, const void* dwc_b,
                        const void* om_w, const void* om_b,
                        const void* outp_w, const void* outp_b,
                        float* __restrict__ W, const int* flagp) {
  const int bf = *flagp;
  const int g0 = blockIdx.x*256 + threadIdx.x, GS = gridDim.x*256;
  for (int i = g0; i < 8192; i += GS) { int c = i>>7, o = i&127;
    W[W1_PW1T + i] = ldin(pw1_w, o*64 + c, bf) * ldin(ln1_g, c, bf); }
  for (int o = g0; o < 128; o += GS) { float s = 0.f;
    for (int c = 0; c < 64; ++c) s += ldin(pw1_w, o*64+c, bf) * ldin(ln1_g, c, bf);
    W[W1_RS1 + o] = s; W[W1_PB1 + o] = ldin(pw1_b, o, bf); }
  for (int i = g0; i < 16384; i += GS) { int c = i>>7, o = i&127;
    W[W1_VALT + i] = ldin(val_w, o*128 + c, bf); }
  for (int i = g0; i < 128; i += GS) W[W1_VB + i] = ldin(val_b, i, bf);
  for (int i = g0; i < 1152; i += GS) W[W1_DWC + i] = ldin(dwc_w, i, bf);
  for (int i = g0; i < 128; i += GS) W[W1_DWB + i] = ldin(dwc_b, i, bf);
  for (int i = g0; i < 13824; i += GS) { int c = i/108, o = i%108;
    W[W1_OMT + i] = ldin(om_w, o*128 + c, bf); }
  for (int i = g0; i < 108; i += GS) W[W1_OMB + i] = ldin(om_b, i, bf);
  for (int i = g0; i < 16384; i += GS) { int c = i>>7, o = i&127;
    W[W1_OUTT + i] = ldin(outp_w, o*128 + c, bf); }
  for (int i = g0; i < 128; i += GS) W[W1_OUTB + i] = ldin(outp_b, i, bf);
}

// ---- weight conversion, phase 2 (into Bv+26000)
__global__ void k_conv2(const void* outp_w, const void* outp_b,
                        const void* conv3_w, const void* conv3_b, const void* beta,
                        const void* norm2_g, const void* conv4_w, const void* conv4_b,
                        const void* conv5_w, const void* conv5_b, const void* gamma,
                        float* __restrict__ W, const int* flagp) {
  const int bf = *flagp;
  const int g0 = blockIdx.x*256 + threadIdx.x, GS = gridDim.x*256;
  for (int i = g0; i < 16384; i += GS) { int c = i>>7, o = i&127;
    W[WB_OUTT + i] = ldin(outp_w, o*128 + c, bf); }
  for (int i = g0; i < 128; i += GS) W[WB_OUTB + i] = ldin(outp_b, i, bf);
  for (int i = g0; i < 8192; i += GS) { int c = i>>6, o = i&63;
    W[WB_C3T + i] = ldin(conv3_w, o*128 + c, bf); }
  for (int i = g0; i < 64; i += GS) { W[WB_C3B + i] = ldin(conv3_b, i, bf);
    W[WB_BETA + i] = ldin(beta, i, bf); }
  for (int i = g0; i < 16384; i += GS) { int c = i>>7, o = i&127;
    W[WB_W4T + i] = ldin(conv4_w, o*128 + c, bf) * ldin(norm2_g, c, bf); }
  for (int o = g0; o < 128; o += GS) { float s = 0.f;
    for (int c = 0; c < 128; ++c) s += ldin(conv4_w, o*128+c, bf) * ldin(norm2_g, c, bf);
    W[WB_RS4 + o] = s; W[WB_B4 + o] = ldin(conv4_b, o, bf); }
  for (int i = g0; i < 4096; i += GS) { int c = i>>6, o = i&63;
    W[WB_W5T + i] = ldin(conv5_w, o*64 + c, bf) * ldin(gamma, o, bf); }
  for (int i = g0; i < 64; i += GS)
    W[WB_B5G + i] = ldin(conv5_b, i, bf) * ldin(gamma, i, bf);
}

// ======== channel-major kernels: lane = pixel, wave = output chunk, no LDS ========

// ---- 1a. LN(64)+pw1 -> h1 [128][PN]   grid(800,2)
__global__ __launch_bounds__(256) void k_lnpw1(const void* x, const float* __restrict__ W,
                                               float* __restrict__ h1, const int* flagp) {
  const int bf = *flagp;
  const int lane = threadIdx.x & 63, wv = threadIdx.x >> 6;
  const int pbase = blockIdx.x * 64;
  const int b = pbase / HWn, rem = pbase % HWn + lane;
  const long p = pbase + lane;
  const int obase = __builtin_amdgcn_readfirstlane((blockIdx.y*4 + wv) * 16);
  float s = 0.f, s2 = 0.f;
  for (int c = 0; c < 64; ++c) {
    float a = ldin(x, (long)(b*C0 + c)*HWn + rem, bf);
    s += a; s2 += a*a;
  }
  const float mean = s * (1.f/64.f);
  const float rstd = rsqrtf(s2*(1.f/64.f) - mean*mean + 1e-5f);
  float acc[16] = {};
  #pragma unroll 4
  for (int c = 0; c < 64; ++c) {
    float a = ldin(x, (long)(b*C0 + c)*HWn + rem, bf);
    const float* __restrict__ wr = W + W1_PW1T + c*128 + obase;
    #pragma unroll
    for (int oi = 0; oi < 16; ++oi) acc[oi] += a * wr[oi];
  }
  #pragma unroll
  for (int oi = 0; oi < 16; ++oi)
    h1[(long)(obase+oi)*PN + p] =
      rstd*(acc[oi] - mean*W[W1_RS1+obase+oi]) + W[W1_PB1+obase+oi];
}

// ---- 1b. val: v = h1 @ valT   grid(800,2)
__global__ __launch_bounds__(256) void k_val(const float* __restrict__ h1,
                                             const float* __restrict__ W,
                                             float* __restrict__ vout) {
  const int lane = threadIdx.x & 63, wv = threadIdx.x >> 6;
  const long p = (long)blockIdx.x * 64 + lane;
  const int obase = __builtin_amdgcn_readfirstlane((blockIdx.y*4 + wv) * 16);
  float acc[16] = {};
  #pragma unroll 4
  for (int c = 0; c < 128; ++c) {
    float a = h1[(long)c*PN + p];
    const float* __restrict__ wr = W + W1_VALT + c*128 + obase;
    #pragma unroll
    for (int oi = 0; oi < 16; ++oi) acc[oi] += a * wr[oi];
  }
  #pragma unroll
  for (int oi = 0; oi < 16; ++oi)
    vout[(long)(obase+oi)*PN + p] = acc[oi] + W[W1_VB+obase+oi];
}

// ---- 2. depthwise 3x3 + om head -> om [108][PN]   grid(800)
__global__ __launch_bounds__(256) void k_dwom(const float* __restrict__ h1,
                                              const float* __restrict__ W,
                                              float* __restrict__ om) {
  const int lane = threadIdx.x & 63, wv = threadIdx.x >> 6;
  const int pbase = blockIdx.x * 64;
  const int b = pbase / HWn;
  const int rem = pbase % HWn + lane;
  const int h = rem / WW, w2 = rem % WW;
  const long p = pbase + lane;
  const long brow = (long)b*HWn;
  const int obase = __builtin_amdgcn_readfirstlane(wv * 27);
  float acc[27] = {};
  for (int c = 0; c < 128; ++c) {
    float dw = W[W1_DWB + c];
    #pragma unroll
    for (int ky = 0; ky < 3; ++ky)
      #pragma unroll
      for (int kx = 0; kx < 3; ++kx) {
        int hh = h + ky - 1, ww2 = w2 + kx - 1;
        bool ok = (hh >= 0 && hh < HH && ww2 >= 0 && ww2 < WW);
        float hv = ok ? h1[(long)c*PN + brow + hh*WW + ww2] : 0.f;
        dw += hv * W[W1_DWC + (ky*3+kx)*128 + c];
      }
    const float* __restrict__ wr = W + W1_OMT + c*108 + obase;
    #pragma unroll
    for (int oi = 0; oi < 27; ++oi) acc[oi] += dw * wr[oi];
  }
  #pragma unroll
  for (int oi = 0; oi < 27; ++oi)
    om[(long)(obase+oi)*PN + p] = acc[oi] + W[W1_OMB+obase+oi];
}

// ---- 3. deformable bilinear sampling -> s [128][PN]   grid(800); wave = group
__global__ __launch_bounds__(256) void k_samp(const float* __restrict__ v,
                                              const float* __restrict__ om,
                                              float* __restrict__ sout) {
  const int lane = threadIdx.x & 63, wv = threadIdx.x >> 6;
  const int g = __builtin_amdgcn_readfirstlane(wv);
  const int pbase = blockIdx.x * 64;
  const int b = pbase / HWn;
  const int rem = pbase % HWn + lane;
  const int h = rem / WW, w = rem % WW;
  const long p = pbase + lane;
  const float* __restrict__ vg = v + (long)(g*32)*PN + (long)b*HWn;
  float o27[27];
  #pragma unroll
  for (int j = 0; j < 27; ++j) o27[j] = om[(long)(g*27+j)*PN + p];
  float acc[32] = {};
  #pragma unroll
  for (int k = 0; k < 9; ++k) {
    const float offx = o27[k*3+0], offy = o27[k*3+1], m = o27[k*3+2];
    const float px = (float)(w + (k % 3)) + offx;   // padded coords, Wp=162
    const float py = (float)(h + (k / 3)) + offy;
    const float x0f = floorf(px), y0f = floorf(py);
    const float tx = px - x0f, ty = py - y0f;
    const int x0 = (int)x0f, y0 = (int)y0f;
    #pragma unroll
    for (int dy = 0; dy < 2; ++dy)
      #pragma unroll
      for (int dx = 0; dx < 2; ++dx) {
        const int xi = x0 + dx, yi = y0 + dy;
        if (xi >= 1 && xi <= WW && yi >= 1 && yi <= HH) {
          const float wq = (dx ? tx : 1.f - tx) * (dy ? ty : 1.f - ty) * m;
          const float* __restrict__ vr = vg + (yi-1)*WW + (xi-1);
          #pragma unroll
          for (int c = 0; c < 32; ++c) acc[c] += wq * vr[(long)c*PN];
        }
      }
  }
  #pragma unroll
  for (int c = 0; c < 32; ++c) sout[(long)(g*32+c)*PN + p] = acc[c];
}

// ---- 4. outp + SimpleGate -> f [64][PN]   grid(800,2); wave = 8 gate pairs
__global__ __launch_bounds__(256) void k_outp(const float* __restrict__ s,
                                              const float* __restrict__ wT,
                                              const float* __restrict__ bias,
                                              float* __restrict__ f) {
  const int lane = threadIdx.x & 63, wv = threadIdx.x >> 6;
  const long p = (long)blockIdx.x * 64 + lane;
  const int gb = __builtin_amdgcn_readfirstlane((blockIdx.y*4 + wv) * 8);
  float accL[8] = {}, accH[8] = {};
  #pragma unroll 4
  for (int c = 0; c < 128; ++c) {
    float a = s[(long)c*PN + p];
    const float* __restrict__ wrL = wT + c*128 + gb;
    const float* __restrict__ wrH = wrL + 64;
    #pragma unroll
    for (int oi = 0; oi < 8; ++oi) { accL[oi] += a*wrL[oi]; accH[oi] += a*wrH[oi]; }
  }
  #pragma unroll
  for (int oi = 0; oi < 8; ++oi)
    f[(long)(gb+oi)*PN + p] = (accL[oi] + bias[gb+oi]) * (accH[oi] + bias[64+gb+oi]);
}

// ---- 5a. pool: one block per (b, ch) -> pooled[256]
__global__ __launch_bounds__(256) void k_pool(const float* __restrict__ fL,
                                              const float* __restrict__ fR,
                                              float* __restrict__ pooled) {
  const int blk = blockIdx.x;                 // b*128 + ch
  const int b = blk >> 7, ch = blk & 127;
  const float* __restrict__ row = ((ch < 64) ? fL : fR) + (long)(ch & 63)*PN + (long)b*HWn;
  float s = 0.f;
  for (int i = threadIdx.x; i < HWn; i += 256) s += row[i];
  __shared__ float red[256];
  red[threadIdx.x] = s; __syncthreads();
  for (int k = 128; k > 0; k >>= 1) { if (threadIdx.x < k) red[threadIdx.x] += red[threadIdx.x+k]; __syncthreads(); }
  if (threadIdx.x == 0) pooled[blk] = red[0] / (float)HWn;
}

// ---- 5b. pooled -> scale
__global__ __launch_bounds__(256) void k_scale(const float* __restrict__ pooled,
                                               const void* sca_w, const void* sca_b,
                                               float* __restrict__ scale, const int* flagp) {
  const int bf = *flagp;
  const int t = threadIdx.x, b = t >> 7, o = t & 127;
  float acc = ldin(sca_b, o, bf);
  for (int c = 0; c < 128; ++c) acc += pooled[b*128 + c] * ldin(sca_w, o*128 + c, bf);
  scale[b*128 + o] = acc;
}

// ---- 6. conv3 + residual -> y [128][PN] (rows 0-63 = L, 64-127 = R)   grid(800)
__global__ __launch_bounds__(256) void k_c3y(const float* __restrict__ fL,
                                             const float* __restrict__ fR,
                                             const float* __restrict__ scaleP,
                                             const float* __restrict__ W,
                                             const void* x_l, const void* x_r,
                                             float* __restrict__ y, const int* flagp) {
  const int bf = *flagp;
  const int lane = threadIdx.x & 63, wv = threadIdx.x >> 6;
  const int pbase = blockIdx.x * 64;
  const int b = pbase / HWn, rem = pbase % HWn + lane;
  const long p = pbase + lane;
  const int o16 = __builtin_amdgcn_readfirstlane(wv * 16);
  float acc[16] = {};
  #pragma unroll 4
  for (int c = 0; c < 64; ++c) {
    float a = fL[(long)c*PN + p] * scaleP[b*128 + c];
    const float* __restrict__ wr = W + WB_C3T + c*64 + o16;
    #pragma unroll
    for (int oi = 0; oi < 16; ++oi) acc[oi] += a * wr[oi];
  }
  #pragma unroll 4
  for (int c = 64; c < 128; ++c) {
    float a = fR[(long)(c-64)*PN + p] * scaleP[b*128 + c];
    const float* __restrict__ wr = W + WB_C3T + c*64 + o16;
    #pragma unroll
    for (int oi = 0; oi < 16; ++oi) acc[oi] += a * wr[oi];
  }
  #pragma unroll
  for (int oi = 0; oi < 16; ++oi) {
    const int o = o16 + oi;
    const float x3b = (acc[oi] + W[WB_C3B+o]) * W[WB_BETA+o];
    y[(long)o*PN + p]      = ldin(x_l, (long)(b*C0+o)*HWn + rem, bf) + x3b;
    y[(long)(64+o)*PN + p] = ldin(x_r, (long)(b*C0+o)*HWn + rem, bf) + x3b;
  }
}

// ---- 7. LN(128) + conv4 + SimpleGate -> sg [64][PN]   grid(800,2)
__global__ __launch_bounds__(256) void k_ln2c4(const float* __restrict__ y,
                                               const float* __restrict__ W,
                                               float* __restrict__ sg) {
  const int lane = threadIdx.x & 63, wv = threadIdx.x >> 6;
  const long p = (long)blockIdx.x * 64 + lane;
  const int gb = __builtin_amdgcn_readfirstlane((blockIdx.y*4 + wv) * 8);
  float s = 0.f, s2 = 0.f;
  for (int c = 0; c < 128; ++c) {
    float a = y[(long)c*PN + p];
    s += a; s2 += a*a;
  }
  const float mean = s * (1.f/128.f);
  const float rstd = rsqrtf(s2*(1.f/128.f) - mean*mean + 1e-5f);
  float accL[8] = {}, accH[8] = {};
  #pragma unroll 4
  for (int c = 0; c < 128; ++c) {
    float a = y[(long)c*PN + p];
    const float* __restrict__ wrL = W + WB_W4T + c*128 + gb;
    const float* __restrict__ wrH = wrL + 64;
    #pragma unroll
    for (int oi = 0; oi < 8; ++oi) { accL[oi] += a*wrL[oi]; accH[oi] += a*wrH[oi]; }
  }
  #pragma unroll
  for (int oi = 0; oi < 8; ++oi) {
    float tl = rstd*(accL[oi] - mean*W[WB_RS4+gb+oi])    + W[WB_B4+gb+oi];
    float th = rstd*(accH[oi] - mean*W[WB_RS4+64+gb+oi]) + W[WB_B4+64+gb+oi];
    sg[(long)(gb+oi)*PN + p] = tl * th;
  }
}

// ---- 8. conv5 (gamma folded) + residual -> dout NCHW   grid(800)
__global__ __launch_bounds__(256) void k_c5out(const float* __restrict__ sg,
                                               const float* __restrict__ y,
                                               const float* __restrict__ W,
                                               void* dout, const int* flagp) {
  const int bf = *flagp;
  const int lane = threadIdx.x & 63, wv = threadIdx.x >> 6;
  const int pbase = blockIdx.x * 64;
  const int b = pbase / HWn, rem = pbase % HWn + lane;
  const long p = pbase + lane;
  const int o16 = __builtin_amdgcn_readfirstlane(wv * 16);
  float acc[16] = {};
  #pragma unroll 4
  for (int c = 0; c < 64; ++c) {
    float a = sg[(long)c*PN + p];
    const float* __restrict__ wr = W + WB_W5T + c*64 + o16;
    #pragma unroll
    for (int oi = 0; oi < 16; ++oi) acc[oi] += a * wr[oi];
  }
  #pragma unroll
  for (int oi = 0; oi < 16; ++oi) {
    const int o = o16 + oi;
    const float z = acc[oi] + W[WB_B5G+o];
    const float outL = y[(long)o*PN + p] + z;
    const float outR = y[(long)(64+o)*PN + p] + z;
    stout(dout, (long)(b*C0+o)*HWn + rem, outL, bf);
    stout(dout, (long)BN*C0*HWn + (long)(b*C0+o)*HWn + rem, outR, bf);
  }
}

extern "C" void kernel_launch(void* const* d_in, const int* in_sizes, int n_in,
                              void* d_out, int out_size, void* d_ws, size_t ws_size,
                              hipStream_t stream) {
  const void* x_l    = d_in[0];
  const void* x_r    = d_in[1];
  const void* ln1_g  = d_in[2];
  const void* pw1_w  = d_in[3];
  const void* pw1_b  = d_in[4];
  const void* val_w  = d_in[5];
  const void* val_b  = d_in[6];
  const void* dwc_w  = d_in[7];
  const void* dwc_b  = d_in[8];
  const void* om_w   = d_in[9];
  const void* om_b   = d_in[10];
  const void* outp_w = d_in[11];
  const void* outp_b = d_in[12];
  const void* sca_w  = d_in[13];
  const void* sca_b  = d_in[14];
  const void* conv3_w = d_in[15];
  const void* conv3_b = d_in[16];
  const void* norm2_g = d_in[17];
  const void* conv4_w = d_in[18];
  const void* conv4_b = d_in[19];
  const void* conv5_w = d_in[20];
  const void* conv5_b = d_in[21];
  const void* beta   = d_in[22];
  const void* gamma  = d_in[23];

  int* flag  = (int*)d_ws;
  float* wsf = (float*)((char*)d_ws + 1024);
  // Regions (same peak footprint as round-6 passing version), all channel-major [ch][PN]:
  float* A  = wsf;                       // h1 -> s -> y
  float* Bv = wsf + S128;                // v -> pooled/scale/WB/sg
  float* Cm = wsf + 2*S128;              // om [108][PN]
  float* fL = wsf + 2*S128 + S108;
  float* fR = fL + S64v;
  float* W1 = fR;                        // phase-1 weights live in fR until side-1 k_outp writes fR
  float* WB = Bv + 26000;                // phase-2 weights (v dead after side-1 k_samp)
  float* pooled = Bv;                    // 256 floats
  float* scaleP = Bv + 512;              // 256 floats
  float* sgP    = Bv + 200000;           // 64*PN floats (disjoint from WB: 26000+45632 < 200000)

  hipLaunchKernelGGL(k_flag, dim3(1), dim3(1), 0, stream, ln1_g, flag);
  hipLaunchKernelGGL(k_conv1, dim3(64), dim3(256), 0, stream,
                     pw1_w, ln1_g, pw1_b, val_w, val_b, dwc_w, dwc_b,
                     om_w, om_b, outp_w, outp_b, W1, flag);

  // side 0
  hipLaunchKernelGGL(k_lnpw1, dim3(800,2), dim3(256), 0, stream, x_l, W1, A, flag);
  hipLaunchKernelGGL(k_val,   dim3(800,2), dim3(256), 0, stream, A, W1, Bv);
  hipLaunchKernelGGL(k_dwom,  dim3(800),   dim3(256), 0, stream, A, W1, Cm);
  hipLaunchKernelGGL(k_samp,  dim3(800),   dim3(256), 0, stream, Bv, Cm, A);
  hipLaunchKernelGGL(k_outp,  dim3(800,2), dim3(256), 0, stream, A, W1 + W1_OUTT, W1 + W1_OUTB, fL);
  // side 1
  hipLaunchKernelGGL(k_lnpw1, dim3(800,2), dim3(256), 0, stream, x_r, W1, A, flag);
  hipLaunchKernelGGL(k_val,   dim3(800,2), dim3(256), 0, stream, A, W1, Bv);
  hipLaunchKernelGGL(k_dwom,  dim3(800),   dim3(256), 0, stream, A, W1, Cm);
  hipLaunchKernelGGL(k_samp,  dim3(800),   dim3(256), 0, stream, Bv, Cm, A);
  hipLaunchKernelGGL(k_conv2, dim3(64),    dim3(256), 0, stream,
                     outp_w, outp_b, conv3_w, conv3_b, beta, norm2_g,
                     conv4_w, conv4_b, conv5_w, conv5_b, gamma, WB, flag);
  hipLaunchKernelGGL(k_outp,  dim3(800,2), dim3(256), 0, stream, A, WB + WB_OUTT, WB + WB_OUTB, fR);

  hipLaunchKernelGGL(k_pool,  dim3(256),   dim3(256), 0, stream, fL, fR, pooled);
  hipLaunchKernelGGL(k_scale, dim3(1),     dim3(256), 0, stream, pooled, sca_w, sca_b, scaleP, flag);
  hipLaunchKernelGGL(k_c3y,   dim3(800),   dim3(256), 0, stream, fL, fR, scaleP, WB,
                     x_l, x_r, A, flag);
  hipLaunchKernelGGL(k_ln2c4, dim3(800,2), dim3(256), 0, stream, A, WB, sgP);
  hipLaunchKernelGGL(k_c5out, dim3(800),   dim3(256), 0, stream, sgP, A, WB, d_out, flag);
}

// Round 8
// 610.174 us; speedup vs baseline: 1.5637x; 1.5637x over previous
//
#include <hip/hip_runtime.h>
#include <hip/hip_bf16.h>

#define BN 2
#define C0 64
#define HH 160
#define WW 160
#define HWn (HH*WW)          // 25600
#define PN (BN*HWn)          // 51200
#define DWCH 128
#define OMC 108
#define PPB 64
#define NB (PN/PPB)          // 800

#define S128 ((long)PN*128)
#define S108 ((long)PN*108)
#define S64v ((long)PN*64)

// ---- phase-1 weight pack (lives in fR region; fR written only by side-1 k_outp)
#define W1_PW1T   0        // [64c][128o] pw1_w * ln1_g[c], transposed
#define W1_RS1    8192     // [128] rowsum of pw1T over c
#define W1_PB1    8320     // [128]
#define W1_VALT   8448     // [128c][128o]
#define W1_VB     24832    // [128]
#define W1_DWC    24960    // [1152]
#define W1_DWB    26112    // [128]
#define W1_OMT    26240    // [128c][108o]
#define W1_OMB    40064    // [108]
#define W1_OUTT   40172    // [128c][128o]
#define W1_OUTB   56556    // [128]
// ---- phase-2 weight pack (Bv+26000; v dead after side-1 k_samp4)
#define WB_OUTT   0        // [128c][128o]
#define WB_OUTB   16384
#define WB_C3T    16512    // [128c][64o]
#define WB_C3B    24704
#define WB_BETA   24768
#define WB_W4T    24832    // [128c][128o] conv4_w * norm2_g[c], transposed
#define WB_RS4    41216
#define WB_B4     41344
#define WB_W5T    41472    // [64c][64o] conv5_w * gamma[o], transposed
#define WB_B5G    45568    // [64] conv5_b * gamma

__device__ __forceinline__ float ldin(const void* p, long i, int bf) {
  return bf ? __bfloat162float(((const __hip_bfloat16*)p)[i])
            : ((const float*)p)[i];
}
__device__ __forceinline__ void stout(void* p, long i, float v, int bf) {
  if (bf) ((__hip_bfloat16*)p)[i] = __float2bfloat16(v);
  else    ((float*)p)[i] = v;
}

// ---- dtype probe
__global__ void k_flag(const void* g1, int* flag) {
  unsigned w = *(const unsigned*)g1;
  *flag = (w == 0x3F800000u) ? 0 : 1;
}

// ---- weight conversion, phase 1 (into fR region)
__global__ void k_conv1(const void* pw1_w, const void* ln1_g, const void* pw1_b,
                        const void* val_w, const void* val_b,
                        const void* dwc_w, const void* dwc_b,
                        const void* om_w, const void* om_b,
                        const void* outp_w, const void* outp_b,
                        float* __restrict__ W, const int* flagp) {
  const int bf = *flagp;
  const int g0 = blockIdx.x*256 + threadIdx.x, GS = gridDim.x*256;
  for (int i = g0; i < 8192; i += GS) { int c = i>>7, o = i&127;
    W[W1_PW1T + i] = ldin(pw1_w, o*64 + c, bf) * ldin(ln1_g, c, bf); }
  for (int o = g0; o < 128; o += GS) { float s = 0.f;
    for (int c = 0; c < 64; ++c) s += ldin(pw1_w, o*64+c, bf) * ldin(ln1_g, c, bf);
    W[W1_RS1 + o] = s; W[W1_PB1 + o] = ldin(pw1_b, o, bf); }
  for (int i = g0; i < 16384; i += GS) { int c = i>>7, o = i&127;
    W[W1_VALT + i] = ldin(val_w, o*128 + c, bf); }
  for (int i = g0; i < 128; i += GS) W[W1_VB + i] = ldin(val_b, i, bf);
  for (int i = g0; i < 1152; i += GS) W[W1_DWC + i] = ldin(dwc_w, i, bf);
  for (int i = g0; i < 128; i += GS) W[W1_DWB + i] = ldin(dwc_b, i, bf);
  for (int i = g0; i < 13824; i += GS) { int c = i/108, o = i%108;
    W[W1_OMT + i] = ldin(om_w, o*128 + c, bf); }
  for (int i = g0; i < 108; i += GS) W[W1_OMB + i] = ldin(om_b, i, bf);
  for (int i = g0; i < 16384; i += GS) { int c = i>>7, o = i&127;
    W[W1_OUTT + i] = ldin(outp_w, o*128 + c, bf); }
  for (int i = g0; i < 128; i += GS) W[W1_OUTB + i] = ldin(outp_b, i, bf);
}

// ---- weight conversion, phase 2 (into Bv+26000)
__global__ void k_conv2(const void* outp_w, const void* outp_b,
                        const void* conv3_w, const void* conv3_b, const void* beta,
                        const void* norm2_g, const void* conv4_w, const void* conv4_b,
                        const void* conv5_w, const void* conv5_b, const void* gamma,
                        float* __restrict__ W, const int* flagp) {
  const int bf = *flagp;
  const int g0 = blockIdx.x*256 + threadIdx.x, GS = gridDim.x*256;
  for (int i = g0; i < 16384; i += GS) { int c = i>>7, o = i&127;
    W[WB_OUTT + i] = ldin(outp_w, o*128 + c, bf); }
  for (int i = g0; i < 128; i += GS) W[WB_OUTB + i] = ldin(outp_b, i, bf);
  for (int i = g0; i < 8192; i += GS) { int c = i>>6, o = i&63;
    W[WB_C3T + i] = ldin(conv3_w, o*128 + c, bf); }
  for (int i = g0; i < 64; i += GS) { W[WB_C3B + i] = ldin(conv3_b, i, bf);
    W[WB_BETA + i] = ldin(beta, i, bf); }
  for (int i = g0; i < 16384; i += GS) { int c = i>>7, o = i&127;
    W[WB_W4T + i] = ldin(conv4_w, o*128 + c, bf) * ldin(norm2_g, c, bf); }
  for (int o = g0; o < 128; o += GS) { float s = 0.f;
    for (int c = 0; c < 128; ++c) s += ldin(conv4_w, o*128+c, bf) * ldin(norm2_g, c, bf);
    W[WB_RS4 + o] = s; W[WB_B4 + o] = ldin(conv4_b, o, bf); }
  for (int i = g0; i < 4096; i += GS) { int c = i>>6, o = i&63;
    W[WB_W5T + i] = ldin(conv5_w, o*64 + c, bf) * ldin(gamma, o, bf); }
  for (int i = g0; i < 64; i += GS)
    W[WB_B5G + i] = ldin(conv5_b, i, bf) * ldin(gamma, i, bf);
}

// ---- 1. LN(64) + pw1 (64->128) + val (128->128) -> h1, v  [8 waves, 16 o/thread]
__global__ __launch_bounds__(512, 6) void k_lnpw1v(const void* x, const float* __restrict__ W,
                                                   float* __restrict__ h1, float* __restrict__ vout,
                                                   const int* flagp) {
  const int bf = *flagp;
  const int tid = threadIdx.x, lane = tid & 63;
  const int pbase = blockIdx.x * PPB;
  const int b = pbase / HWn, rem0 = pbase % HWn;
  __shared__ float buf[8256];   // raw x (stride 65) -> h1 (stride 129) -> v (stride 129)
  __shared__ float st[1152];    // ps[512], ps2[512], mean[64]@1024, rstd[64]@1088
  for (int it = 0; it < 8; ++it) {
    int idx = it*512 + tid;     // 4096 = 64c x 64p
    int c = idx >> 6, p = idx & 63;
    buf[p*65 + c] = ldin(x, (long)(b*C0 + c)*HWn + rem0 + p, bf);
  }
  __syncthreads();
  {
    int p = tid & 63, cg = tid >> 6;
    float s = 0.f, s2 = 0.f;
    #pragma unroll
    for (int j = 0; j < 8; ++j) { float v = buf[p*65 + cg*8 + j]; s += v; s2 += v*v; }
    st[cg*64 + p] = s; st[512 + cg*64 + p] = s2;
  }
  __syncthreads();
  if (tid < 64) {
    float s = 0.f, s2 = 0.f;
    #pragma unroll
    for (int cg = 0; cg < 8; ++cg) { s += st[cg*64 + tid]; s2 += st[512 + cg*64 + tid]; }
    float mean = s * (1.f/64.f);
    float rstd = rsqrtf(s2 * (1.f/64.f) - mean*mean + 1e-5f);
    st[1024 + tid] = mean; st[1088 + tid] = rstd;
  }
  __syncthreads();
  const int obase = __builtin_amdgcn_readfirstlane((tid >> 6) * 16);
  const float mean = st[1024 + lane], rstd = st[1088 + lane];
  float acc[16] = {};
  for (int c = 0; c < 64; ++c) {
    const float a = buf[lane*65 + c];
    const float* __restrict__ wr = W + W1_PW1T + c*128 + obase;
    #pragma unroll
    for (int oi = 0; oi < 16; ++oi) acc[oi] += a * wr[oi];
  }
  __syncthreads();   // all stride-65 reads done
  #pragma unroll
  for (int oi = 0; oi < 16; ++oi)
    buf[lane*129 + obase + oi] =
      rstd*(acc[oi] - mean*W[W1_RS1 + obase + oi]) + W[W1_PB1 + obase + oi];
  __syncthreads();
  for (int it = 0; it < 4; ++it) {
    int idx = it*512 + tid;     // 2048 f4
    int p = idx >> 5, c4 = idx & 31;
    const float* sp = &buf[p*129 + c4*4];
    *(float4*)&h1[(long)(pbase+p)*128 + c4*4] = make_float4(sp[0],sp[1],sp[2],sp[3]);
  }
  float acc2[16] = {};
  for (int c = 0; c < 128; ++c) {
    const float a = buf[lane*129 + c];
    const float* __restrict__ wr = W + W1_VALT + c*128 + obase;
    #pragma unroll
    for (int oi = 0; oi < 16; ++oi) acc2[oi] += a * wr[oi];
  }
  __syncthreads();
  #pragma unroll
  for (int oi = 0; oi < 16; ++oi)
    buf[lane*129 + obase + oi] = acc2[oi] + W[W1_VB + obase + oi];
  __syncthreads();
  for (int it = 0; it < 4; ++it) {
    int idx = it*512 + tid;
    int p = idx >> 5, c4 = idx & 31;
    const float* sp = &buf[p*129 + c4*4];
    *(float4*)&vout[(long)(pbase+p)*128 + c4*4] = make_float4(sp[0],sp[1],sp[2],sp[3]);
  }
}

// ---- 2. depthwise 3x3 (float4) + om head (128->108)  [8 waves, 14/13 o/thread]
__global__ __launch_bounds__(512, 6) void k_dwom4(const float* __restrict__ h1,
                                                  const float* __restrict__ W,
                                                  float* __restrict__ om) {
  const int tid = threadIdx.x, lane = tid & 63;
  const int pbase = blockIdx.x * PPB;
  const int b = pbase / HWn, rem0 = pbase % HWn;
  __shared__ float buf[8256];
  __shared__ float dww[1280];
  for (int i = tid; i < 1280; i += 512)
    dww[i] = (i < 1152) ? W[W1_DWC + i] : W[W1_DWB + i - 1152];
  __syncthreads();
  for (int it = 0; it < 4; ++it) {
    int idx = it*512 + tid;          // 2048 = 64 px x 32 ch4-slots
    int p = idx >> 5, c = (idx & 31)*4;
    int rem = rem0 + p, h = rem / WW, w2 = rem % WW;
    float4 a4 = *(const float4*)&dww[1152 + c];
    #pragma unroll
    for (int ky = 0; ky < 3; ++ky) {
      int hh = h + ky - 1;
      if (hh < 0 || hh >= HH) continue;
      #pragma unroll
      for (int kx = 0; kx < 3; ++kx) {
        int ww2 = w2 + kx - 1;
        if (ww2 < 0 || ww2 >= WW) continue;
        float4 hv = *(const float4*)&h1[(long)(b*HWn + hh*WW + ww2)*128 + c];
        float4 wv = *(const float4*)&dww[(ky*3+kx)*128 + c];
        a4.x += hv.x*wv.x; a4.y += hv.y*wv.y; a4.z += hv.z*wv.z; a4.w += hv.w*wv.w;
      }
    }
    float* d = &buf[p*129 + c];
    d[0]=a4.x; d[1]=a4.y; d[2]=a4.z; d[3]=a4.w;
  }
  __syncthreads();
  const int wv = tid >> 6;
  const int cnt = (wv < 4) ? 14 : 13;
  const int obase = __builtin_amdgcn_readfirstlane((wv < 4) ? wv*14 : 56 + (wv-4)*13);
  float acc[14] = {};
  for (int c = 0; c < 128; ++c) {
    const float a = buf[lane*129 + c];
    const float* __restrict__ wr = W + W1_OMT + c*108 + obase;
    #pragma unroll
    for (int oi = 0; oi < 14; ++oi) acc[oi] += a * wr[oi];  // oi=13 on wave7 reads next row start (valid mem), discarded
  }
  __syncthreads();
  #pragma unroll
  for (int oi = 0; oi < 14; ++oi)
    if (oi < cnt) buf[lane*129 + obase + oi] = acc[oi] + W[W1_OMB + obase + oi];
  __syncthreads();
  for (int it = 0; it < 14; ++it) {
    int idx = it*512 + tid;          // 6912 = 64*108
    if (idx < 6912) {
      int p = idx / 108, o = idx % 108;
      om[(long)(pbase+p)*108 + o] = buf[p*129 + o];
    }
  }
}

// ---- 3. deformable bilinear sampling (float4, 8 px/block, tiny LDS) -> s [P][128]
__global__ __launch_bounds__(256) void k_samp4(const float* __restrict__ v,
                                               const float* __restrict__ om,
                                               float* __restrict__ sout) {
  const int tid = threadIdx.x;
  const long pb = (long)blockIdx.x * 8;
  const int b = (int)(pb / HWn);
  __shared__ float oml[864];           // om for 8 px
  for (int i = tid; i < 864; i += 256) oml[i] = om[pb*108 + i];
  __syncthreads();
  const int p8 = tid >> 5, slot = tid & 31;
  const int g = slot >> 3, c = g*32 + (slot & 7)*4;
  const long p = pb + p8;
  const int rem = (int)(p % HWn), h = rem / WW, w = rem % WW;
  const float* vb = v + (long)b*HWn*128;
  const float* op = &oml[p8*108 + g*27];
  float4 acc = make_float4(0.f, 0.f, 0.f, 0.f);
  #pragma unroll
  for (int k = 0; k < 9; ++k) {
    const float offx = op[k*3+0], offy = op[k*3+1], m = op[k*3+2];
    const float px = (float)(w + (k % 3)) + offx;   // padded coords, Wp=162
    const float py = (float)(h + (k / 3)) + offy;
    const float x0f = floorf(px), y0f = floorf(py);
    const float tx = px - x0f, ty = py - y0f;
    const int x0 = (int)x0f, y0 = (int)y0f;
    #pragma unroll
    for (int dy = 0; dy < 2; ++dy)
      #pragma unroll
      for (int dx = 0; dx < 2; ++dx) {
        const int xi = x0 + dx, yi = y0 + dy;
        if (xi >= 1 && xi <= WW && yi >= 1 && yi <= HH) {
          const float wq = (dx ? tx : 1.f - tx) * (dy ? ty : 1.f - ty) * m;
          const float4 v4 = *(const float4*)&vb[(long)((yi-1)*WW + (xi-1))*128 + c];
          acc.x += wq*v4.x; acc.y += wq*v4.y; acc.z += wq*v4.z; acc.w += wq*v4.w;
        }
      }
  }
  *(float4*)&sout[p*128 + c] = acc;
}

// ---- 4. outp (128->128) + SimpleGate -> f [64][PN] (CHANNEL-MAJOR out)  [8 waves]
__global__ __launch_bounds__(512, 6) void k_outp(const float* __restrict__ s,
                                                 const float* __restrict__ wT,
                                                 const float* __restrict__ bias,
                                                 float* __restrict__ f) {
  const int tid = threadIdx.x, lane = tid & 63;
  const int pbase = blockIdx.x * PPB;
  __shared__ float buf[8256];
  for (int it = 0; it < 4; ++it) {
    int idx = it*512 + tid;     // 2048 f4
    int p = idx >> 5, c4 = idx & 31;
    float4 v = *(const float4*)&s[(long)(pbase+p)*128 + c4*4];
    float* d = &buf[p*129 + c4*4];
    d[0]=v.x; d[1]=v.y; d[2]=v.z; d[3]=v.w;
  }
  __syncthreads();
  const int obase = __builtin_amdgcn_readfirstlane((tid >> 6) * 16);
  float acc[16] = {};
  for (int c = 0; c < 128; ++c) {
    const float a = buf[lane*129 + c];
    const float* __restrict__ wr = wT + c*128 + obase;
    #pragma unroll
    for (int oi = 0; oi < 16; ++oi) acc[oi] += a * wr[oi];
  }
  __syncthreads();
  #pragma unroll
  for (int oi = 0; oi < 16; ++oi)
    buf[lane*129 + obase + oi] = acc[oi] + bias[obase + oi];
  __syncthreads();
  // channel-major store: lanes along p (coalesced); LDS read stride 129 (conflict-free)
  for (int it = 0; it < 8; ++it) {
    int idx = it*512 + tid;     // 4096
    int c = idx >> 6, p = idx & 63;
    f[(long)c*PN + pbase + p] = buf[p*129 + c] * buf[p*129 + 64 + c];
  }
}

// ---- 5a. pool: one block per (b, ch) over CM rows -> pooled[256]
__global__ __launch_bounds__(256) void k_pool(const float* __restrict__ fL,
                                              const float* __restrict__ fR,
                                              float* __restrict__ pooled) {
  const int blk = blockIdx.x;                 // b*128 + ch
  const int b = blk >> 7, ch = blk & 127;
  const float* __restrict__ row = ((ch < 64) ? fL : fR) + (long)(ch & 63)*PN + (long)b*HWn;
  float s = 0.f;
  for (int i = threadIdx.x; i < HWn; i += 256) s += row[i];
  __shared__ float red[256];
  red[threadIdx.x] = s; __syncthreads();
  for (int k = 128; k > 0; k >>= 1) { if (threadIdx.x < k) red[threadIdx.x] += red[threadIdx.x+k]; __syncthreads(); }
  if (threadIdx.x == 0) pooled[blk] = red[0] / (float)HWn;
}

// ---- 5b. pooled -> scale
__global__ __launch_bounds__(256) void k_scale(const float* __restrict__ pooled,
                                               const void* sca_w, const void* sca_b,
                                               float* __restrict__ scale, const int* flagp) {
  const int bf = *flagp;
  const int t = threadIdx.x, b = t >> 7, o = t & 127;
  float acc = ldin(sca_b, o, bf);
  for (int c = 0; c < 128; ++c) acc += pooled[b*128 + c] * ldin(sca_w, o*128 + c, bf);
  scale[b*128 + o] = acc;
}

// ---- 6. conv3 + residual -> y [128][PN] (rows 0-63 = L, 64-127 = R)   grid(800)
__global__ __launch_bounds__(256) void k_c3y(const float* __restrict__ fL,
                                             const float* __restrict__ fR,
                                             const float* __restrict__ scaleP,
                                             const float* __restrict__ W,
                                             const void* x_l, const void* x_r,
                                             float* __restrict__ y, const int* flagp) {
  const int bf = *flagp;
  const int lane = threadIdx.x & 63, wv = threadIdx.x >> 6;
  const int pbase = blockIdx.x * 64;
  const int b = pbase / HWn, rem = pbase % HWn + lane;
  const long p = pbase + lane;
  const int o16 = __builtin_amdgcn_readfirstlane(wv * 16);
  float acc[16] = {};
  #pragma unroll 4
  for (int c = 0; c < 64; ++c) {
    float a = fL[(long)c*PN + p] * scaleP[b*128 + c];
    const float* __restrict__ wr = W + WB_C3T + c*64 + o16;
    #pragma unroll
    for (int oi = 0; oi < 16; ++oi) acc[oi] += a * wr[oi];
  }
  #pragma unroll 4
  for (int c = 64; c < 128; ++c) {
    float a = fR[(long)(c-64)*PN + p] * scaleP[b*128 + c];
    const float* __restrict__ wr = W + WB_C3T + c*64 + o16;
    #pragma unroll
    for (int oi = 0; oi < 16; ++oi) acc[oi] += a * wr[oi];
  }
  #pragma unroll
  for (int oi = 0; oi < 16; ++oi) {
    const int o = o16 + oi;
    const float x3b = (acc[oi] + W[WB_C3B+o]) * W[WB_BETA+o];
    y[(long)o*PN + p]      = ldin(x_l, (long)(b*C0+o)*HWn + rem, bf) + x3b;
    y[(long)(64+o)*PN + p] = ldin(x_r, (long)(b*C0+o)*HWn + rem, bf) + x3b;
  }
}

// ---- 7. LN(128) + conv4 + SimpleGate -> sg [64][PN]   grid(800,2)
__global__ __launch_bounds__(256) void k_ln2c4(const float* __restrict__ y,
                                               const float* __restrict__ W,
                                               float* __restrict__ sg) {
  const int lane = threadIdx.x & 63, wv = threadIdx.x >> 6;
  const long p = (long)blockIdx.x * 64 + lane;
  const int gb = __builtin_amdgcn_readfirstlane((blockIdx.y*4 + wv) * 8);
  float s = 0.f, s2 = 0.f;
  for (int c = 0; c < 128; ++c) {
    float a = y[(long)c*PN + p];
    s += a; s2 += a*a;
  }
  const float mean = s * (1.f/128.f);
  const float rstd = rsqrtf(s2*(1.f/128.f) - mean*mean + 1e-5f);
  float accL[8] = {}, accH[8] = {};
  #pragma unroll 4
  for (int c = 0; c < 128; ++c) {
    float a = y[(long)c*PN + p];
    const float* __restrict__ wrL = W + WB_W4T + c*128 + gb;
    const float* __restrict__ wrH = wrL + 64;
    #pragma unroll
    for (int oi = 0; oi < 8; ++oi) { accL[oi] += a*wrL[oi]; accH[oi] += a*wrH[oi]; }
  }
  #pragma unroll
  for (int oi = 0; oi < 8; ++oi) {
    float tl = rstd*(accL[oi] - mean*W[WB_RS4+gb+oi])    + W[WB_B4+gb+oi];
    float th = rstd*(accH[oi] - mean*W[WB_RS4+64+gb+oi]) + W[WB_B4+64+gb+oi];
    sg[(long)(gb+oi)*PN + p] = tl * th;
  }
}

// ---- 8. conv5 (gamma folded) + residual -> dout NCHW   grid(800)
__global__ __launch_bounds__(256) void k_c5out(const float* __restrict__ sg,
                                               const float* __restrict__ y,
                                               const float* __restrict__ W,
                                               void* dout, const int* flagp) {
  const int bf = *flagp;
  const int lane = threadIdx.x & 63, wv = threadIdx.x >> 6;
  const int pbase = blockIdx.x * 64;
  const int b = pbase / HWn, rem = pbase % HWn + lane;
  const long p = pbase + lane;
  const int o16 = __builtin_amdgcn_readfirstlane(wv * 16);
  float acc[16] = {};
  #pragma unroll 4
  for (int c = 0; c < 64; ++c) {
    float a = sg[(long)c*PN + p];
    const float* __restrict__ wr = W + WB_W5T + c*64 + o16;
    #pragma unroll
    for (int oi = 0; oi < 16; ++oi) acc[oi] += a * wr[oi];
  }
  #pragma unroll
  for (int oi = 0; oi < 16; ++oi) {
    const int o = o16 + oi;
    const float z = acc[oi] + W[WB_B5G+o];
    const float outL = y[(long)o*PN + p] + z;
    const float outR = y[(long)(64+o)*PN + p] + z;
    stout(dout, (long)(b*C0+o)*HWn + rem, outL, bf);
    stout(dout, (long)BN*C0*HWn + (long)(b*C0+o)*HWn + rem, outR, bf);
  }
}

extern "C" void kernel_launch(void* const* d_in, const int* in_sizes, int n_in,
                              void* d_out, int out_size, void* d_ws, size_t ws_size,
                              hipStream_t stream) {
  const void* x_l    = d_in[0];
  const void* x_r    = d_in[1];
  const void* ln1_g  = d_in[2];
  const void* pw1_w  = d_in[3];
  const void* pw1_b  = d_in[4];
  const void* val_w  = d_in[5];
  const void* val_b  = d_in[6];
  const void* dwc_w  = d_in[7];
  const void* dwc_b  = d_in[8];
  const void* om_w   = d_in[9];
  const void* om_b   = d_in[10];
  const void* outp_w = d_in[11];
  const void* outp_b = d_in[12];
  const void* sca_w  = d_in[13];
  const void* sca_b  = d_in[14];
  const void* conv3_w = d_in[15];
  const void* conv3_b = d_in[16];
  const void* norm2_g = d_in[17];
  const void* conv4_w = d_in[18];
  const void* conv4_b = d_in[19];
  const void* conv5_w = d_in[20];
  const void* conv5_b = d_in[21];
  const void* beta   = d_in[22];
  const void* gamma  = d_in[23];

  int* flag  = (int*)d_ws;
  float* wsf = (float*)((char*)d_ws + 1024);
  // Regions: A = h1/s (PM) -> y (CM); Bv = v (PM) -> pooled/scale/WB/sg; Cm = om (PM);
  //          fL/fR = f (CM); W1 in fR until side-1 k_outp; WB in dead v.
  float* A  = wsf;
  float* Bv = wsf + S128;
  float* Cm = wsf + 2*S128;
  float* fL = wsf + 2*S128 + S108;
  float* fR = fL + S64v;
  float* W1 = fR;
  float* WB = Bv + 26000;
  float* pooled = Bv;                    // 256 floats
  float* scaleP = Bv + 512;              // 256 floats (disjoint from WB at +26000)
  float* sgP    = Bv + 200000;           // 64*PN floats (26000+45632 < 200000; 200000+3.28M < 6.55M)

  hipLaunchKernelGGL(k_flag, dim3(1), dim3(1), 0, stream, ln1_g, flag);
  hipLaunchKernelGGL(k_conv1, dim3(64), dim3(256), 0, stream,
                     pw1_w, ln1_g, pw1_b, val_w, val_b, dwc_w, dwc_b,
                     om_w, om_b, outp_w, outp_b, W1, flag);

  // side 0 (pixel-major pipeline)
  hipLaunchKernelGGL(k_lnpw1v, dim3(NB),   dim3(512), 0, stream, x_l, W1, A, Bv, flag);
  hipLaunchKernelGGL(k_dwom4,  dim3(NB),   dim3(512), 0, stream, A, W1, Cm);
  hipLaunchKernelGGL(k_samp4,  dim3(PN/8), dim3(256), 0, stream, Bv, Cm, A);
  hipLaunchKernelGGL(k_outp,   dim3(NB),   dim3(512), 0, stream, A, W1 + W1_OUTT, W1 + W1_OUTB, fL);
  // side 1
  hipLaunchKernelGGL(k_lnpw1v, dim3(NB),   dim3(512), 0, stream, x_r, W1, A, Bv, flag);
  hipLaunchKernelGGL(k_dwom4,  dim3(NB),   dim3(512), 0, stream, A, W1, Cm);
  hipLaunchKernelGGL(k_samp4,  dim3(PN/8), dim3(256), 0, stream, Bv, Cm, A);
  hipLaunchKernelGGL(k_conv2,  dim3(64),   dim3(256), 0, stream,
                     outp_w, outp_b, conv3_w, conv3_b, beta, norm2_g,
                     conv4_w, conv4_b, conv5_w, conv5_b, gamma, WB, flag);
  hipLaunchKernelGGL(k_outp,   dim3(NB),   dim3(512), 0, stream, A, WB + WB_OUTT, WB + WB_OUTB, fR);

  // phase 2 (channel-major, barrier-free)
  hipLaunchKernelGGL(k_pool,  dim3(256),   dim3(256), 0, stream, fL, fR, pooled);
  hipLaunchKernelGGL(k_scale, dim3(1),     dim3(256), 0, stream, pooled, sca_w, sca_b, scaleP, flag);
  hipLaunchKernelGGL(k_c3y,   dim3(800),   dim3(256), 0, stream, fL, fR, scaleP, WB,
                     x_l, x_r, A, flag);
  hipLaunchKernelGGL(k_ln2c4, dim3(800,2), dim3(256), 0, stream, A, WB, sgP);
  hipLaunchKernelGGL(k_c5out, dim3(800),   dim3(256), 0, stream, sgP, A, WB, d_out, flag);
}